// Round 6
// baseline (268.858 us; speedup 1.0000x reference)
//
#include <hip/hip_runtime.h>
#include <hip/hip_bf16.h>
#include <math.h>
#include <type_traits>

#define FDIM 128     // in/hid feature dim
#define ODIM 40      // output classes

typedef __attribute__((ext_vector_type(8))) short bf16x8;
typedef __attribute__((ext_vector_type(4))) float f32x4;

// ---- bf16 pack/unpack helpers (manual, RNE) --------------------------------
__device__ __forceinline__ float bf_lo(unsigned v) { return __uint_as_float(v << 16); }
__device__ __forceinline__ float bf_hi(unsigned v) { return __uint_as_float(v & 0xFFFF0000u); }
__device__ __forceinline__ unsigned f2bf(float f) {   // round-to-nearest-even
    unsigned u = __float_as_uint(f);
    return (u + 0x7FFFu + ((u >> 16) & 1u)) >> 16;
}

// ---------------------------------------------------------------------------
// 1) count in-degrees (dst side) with int atomics
// ---------------------------------------------------------------------------
__global__ void count_edges_k(const int* __restrict__ dst, int* __restrict__ count, int E) {
    int e = blockIdx.x * blockDim.x + threadIdx.x;
    if (e < E) atomicAdd(&count[dst[e]], 1);
}

// ---------------------------------------------------------------------------
// 2a) per-chunk (1024-elem) sums of count; fused dinv = rsqrt(deg+1)
// ---------------------------------------------------------------------------
__global__ __launch_bounds__(256) void block_sum_k(const int* __restrict__ count,
                                                   int* __restrict__ blockSums,
                                                   float* __restrict__ dinv, int n) {
    __shared__ int red[256];
    const int tid = threadIdx.x;
    const int base = blockIdx.x * 1024;
    int s = 0;
#pragma unroll
    for (int j = 0; j < 4; ++j) {
        int i = base + j * 256 + tid;
        if (i < n) {
            int c = count[i];
            s += c;
            dinv[i] = rsqrtf((float)(c + 1));
        }
    }
    red[tid] = s;
    __syncthreads();
    for (int off = 128; off > 0; off >>= 1) {
        if (tid < off) red[tid] += red[tid + off];
        __syncthreads();
    }
    if (tid == 0) blockSums[blockIdx.x] = red[0];
}

// ---------------------------------------------------------------------------
// 2b) one-wave exclusive scan of block sums (nb <= 64); writes rowptr[n]=total
// ---------------------------------------------------------------------------
__global__ __launch_bounds__(64) void scan_sums_k(int* __restrict__ blockSums, int nb,
                                                  int* __restrict__ rowptr, int n) {
    int tid = threadIdx.x;
    int orig = (tid < nb) ? blockSums[tid] : 0;
    int v = orig;
#pragma unroll
    for (int off = 1; off < 64; off <<= 1) {
        int u = __shfl_up(v, off);
        if (tid >= off) v += u;
    }
    if (tid < nb) blockSums[tid] = v - orig;      // exclusive offset per chunk
    if (tid == 63) rowptr[n] = v;                 // grand total
}

// ---------------------------------------------------------------------------
// 2c) per-chunk local exclusive scan + chunk offset -> rowptr/cursor
// ---------------------------------------------------------------------------
__global__ __launch_bounds__(256) void scan_chunk_k(const int* __restrict__ count,
                                                    const int* __restrict__ blockOffs,
                                                    int* __restrict__ rowptr,
                                                    int* __restrict__ cursor, int n) {
    __shared__ int ts[256];
    const int tid = threadIdx.x;
    const int base = blockIdx.x * 1024 + tid * 4;
    int c[4];
    int s = 0;
#pragma unroll
    for (int j = 0; j < 4; ++j) {
        int i = base + j;
        c[j] = (i < n) ? count[i] : 0;
        s += c[j];
    }
    ts[tid] = s;
    __syncthreads();
    for (int off = 1; off < 256; off <<= 1) {
        int v = (tid >= off) ? ts[tid - off] : 0;
        __syncthreads();
        ts[tid] += v;
        __syncthreads();
    }
    int excl = ts[tid] - s + blockOffs[blockIdx.x];
#pragma unroll
    for (int j = 0; j < 4; ++j) {
        int i = base + j;
        if (i < n) {
            rowptr[i] = excl;
            cursor[i] = excl;
        }
        excl += c[j];
    }
}

// ---------------------------------------------------------------------------
// 3) fill CSR: src ids grouped by dst
// ---------------------------------------------------------------------------
__global__ void fill_csr_k(const int* __restrict__ src, const int* __restrict__ dst,
                           int* __restrict__ cursor, int* __restrict__ csr_src, int E) {
    int e = blockIdx.x * blockDim.x + threadIdx.x;
    if (e < E) {
        int d = dst[e];
        int p = atomicAdd(&cursor[d], 1);
        csr_src[p] = src[e];
    }
}

// ---------------------------------------------------------------------------
// 3b) convert both W[128][128] fp32 -> Wt[n][k] bf16 in one dispatch
// ---------------------------------------------------------------------------
__global__ __launch_bounds__(256) void convert_wt2_k(const float* __restrict__ W1,
                                                     const float* __restrict__ W2,
                                                     unsigned short* __restrict__ Wt1,
                                                     unsigned short* __restrict__ Wt2) {
    int idx = blockIdx.x * 256 + threadIdx.x;   // 32768 total
    const float* W = (idx < 16384) ? W1 : W2;
    unsigned short* Wt = (idx < 16384) ? Wt1 : Wt2;
    int i = idx & 16383;
    int k = i >> 7, n = i & 127;
    Wt[n * 128 + k] = (unsigned short)f2bf(W[k * 128 + n]);
}

// ---------------------------------------------------------------------------
// 4) MFMA GEMM: Cb[M,128](bf16) = (A[M,128] @ W) * dinv[row]
//    Wt is W transposed, bf16 [n][k]. 64-row tile per 256-thread block.
//    Whole K=128 staged to LDS once; 4 waves x 32 cols; 16x16x32 bf16 MFMA.
// ---------------------------------------------------------------------------
template <typename AT>
__global__ __launch_bounds__(256) void mfma_gemm_k(const AT* __restrict__ A,
                                                   const unsigned short* __restrict__ Wt,
                                                   const float* __restrict__ dinv,
                                                   unsigned short* __restrict__ Cb, int M) {
    __shared__ unsigned short As[64][136];   // row stride 272 B = 4 banks mod 32
    __shared__ unsigned short Bs[128][136];

    const int tid = threadIdx.x;
    const int row0 = blockIdx.x * 64;

    // ---- stage A (64 x 128) ----
    if constexpr (std::is_same_v<AT, float>) {
#pragma unroll
        for (int i = 0; i < 8; ++i) {        // 64 rows * 32 float4 = 2048
            int fidx = i * 256 + tid;
            int r = fidx >> 5, kq = fidx & 31;
            float4 v = make_float4(0.f, 0.f, 0.f, 0.f);
            int grow = row0 + r;
            if (grow < M) v = *(const float4*)&A[(size_t)grow * 128 + kq * 4];
            unsigned lo = f2bf(v.x) | (f2bf(v.y) << 16);
            unsigned hi = f2bf(v.z) | (f2bf(v.w) << 16);
            *(uint2*)&As[r][kq * 4] = make_uint2(lo, hi);
        }
    } else {
#pragma unroll
        for (int i = 0; i < 4; ++i) {        // 64 rows * 16 uint4 = 1024
            int fidx = i * 256 + tid;
            int r = fidx >> 4, kq = fidx & 15;
            uint4 v = make_uint4(0, 0, 0, 0);
            int grow = row0 + r;
            if (grow < M) v = *(const uint4*)&A[(size_t)grow * 128 + kq * 8];
            *(uint4*)&As[r][kq * 8] = v;
        }
    }
    // ---- stage B (128 x 128) ----
#pragma unroll
    for (int i = 0; i < 8; ++i) {            // 128 rows * 16 uint4 = 2048
        int fidx = i * 256 + tid;
        int r = fidx >> 4, kq = fidx & 15;
        *(uint4*)&Bs[r][kq * 8] = *(const uint4*)&Wt[(size_t)r * 128 + kq * 8];
    }
    __syncthreads();

    // ---- compute ----
    const int lane = tid & 63;
    const int wv = tid >> 6;       // wave 0..3 -> cols wv*32 .. +31
    const int n0 = wv * 32;
    const int mrow = lane & 15;
    const int quad = lane >> 4;

    f32x4 acc[4][2];
#pragma unroll
    for (int mt = 0; mt < 4; ++mt)
#pragma unroll
        for (int nt = 0; nt < 2; ++nt) acc[mt][nt] = (f32x4){0.f, 0.f, 0.f, 0.f};

#pragma unroll
    for (int kk = 0; kk < 128; kk += 32) {
        int ko = kk + quad * 8;
        bf16x8 af[4], bf[2];
#pragma unroll
        for (int mt = 0; mt < 4; ++mt) af[mt] = *(const bf16x8*)&As[mt * 16 + mrow][ko];
#pragma unroll
        for (int nt = 0; nt < 2; ++nt) bf[nt] = *(const bf16x8*)&Bs[n0 + nt * 16 + mrow][ko];
#pragma unroll
        for (int mt = 0; mt < 4; ++mt)
#pragma unroll
            for (int nt = 0; nt < 2; ++nt)
                acc[mt][nt] = __builtin_amdgcn_mfma_f32_16x16x32_bf16(af[mt], bf[nt], acc[mt][nt], 0, 0, 0);
    }

    // ---- epilogue: C layout col=lane&15, row=quad*4+reg ----
#pragma unroll
    for (int mt = 0; mt < 4; ++mt) {
#pragma unroll
        for (int reg = 0; reg < 4; ++reg) {
            int grow = row0 + mt * 16 + quad * 4 + reg;
            if (grow < M) {
                float sc = dinv[grow];
#pragma unroll
                for (int nt = 0; nt < 2; ++nt) {
                    int col = n0 + nt * 16 + mrow;
                    Cb[(size_t)grow * 128 + col] = (unsigned short)f2bf(acc[mt][nt][reg] * sc);
                }
            }
        }
    }
}

// ---------------------------------------------------------------------------
// 5) aggregate, 2 nodes per wave: out[d,:] = act(dinv[d]*(g[d,:]+sum g[s,:])+b)
//    Half-wave (32 lanes) per dst node; lane owns 4 channels via uint2 (bf16x4).
//    One wave-load instruction fetches an edge-row for BOTH nodes -> load-issue
//    count per pair = max(deg_a,deg_b) instead of deg_a+deg_b. fp32 accumulate.
// ---------------------------------------------------------------------------
template <bool RELU, bool OUT_BF16>
__global__ __launch_bounds__(64) void aggregate2_k(const uint2* __restrict__ g2,
                                                   const float* __restrict__ dinv,
                                                   const int* __restrict__ rowptr,
                                                   const int* __restrict__ csr_src,
                                                   const float* __restrict__ bias,
                                                   void* __restrict__ outv, int n) {
    const int lane = threadIdx.x;
    const int h = lane & 31;                       // uint2 index within row (32 per row)
    const int d = blockIdx.x * 2 + (lane >> 5);    // node for this half-wave
    const bool valid = d < n;

    float a0 = 0.f, a1 = 0.f, a2 = 0.f, a3 = 0.f;
    int e = 0, end = 0;
    if (valid) {
        uint2 sv = g2[(size_t)d * 32 + h];         // self-loop term
        a0 = bf_lo(sv.x); a1 = bf_hi(sv.x); a2 = bf_lo(sv.y); a3 = bf_hi(sv.y);
        e = rowptr[d];
        end = rowptr[d + 1];
    }
    for (; e + 3 < end; e += 4) {                  // divergent bounds ok (exec mask)
        int s0 = csr_src[e], s1 = csr_src[e + 1], s2 = csr_src[e + 2], s3 = csr_src[e + 3];
        uint2 v0 = g2[(size_t)s0 * 32 + h];
        uint2 v1 = g2[(size_t)s1 * 32 + h];
        uint2 v2 = g2[(size_t)s2 * 32 + h];
        uint2 v3 = g2[(size_t)s3 * 32 + h];
        a0 += (bf_lo(v0.x) + bf_lo(v1.x)) + (bf_lo(v2.x) + bf_lo(v3.x));
        a1 += (bf_hi(v0.x) + bf_hi(v1.x)) + (bf_hi(v2.x) + bf_hi(v3.x));
        a2 += (bf_lo(v0.y) + bf_lo(v1.y)) + (bf_lo(v2.y) + bf_lo(v3.y));
        a3 += (bf_hi(v0.y) + bf_hi(v1.y)) + (bf_hi(v2.y) + bf_hi(v3.y));
    }
    for (; e < end; ++e) {
        uint2 v = g2[(size_t)csr_src[e] * 32 + h];
        a0 += bf_lo(v.x); a1 += bf_hi(v.x); a2 += bf_lo(v.y); a3 += bf_hi(v.y);
    }
    if (valid) {
        float sc = dinv[d];
        float4 bb = ((const float4*)bias)[h];
        float o0 = fmaf(sc, a0, bb.x);
        float o1 = fmaf(sc, a1, bb.y);
        float o2 = fmaf(sc, a2, bb.z);
        float o3 = fmaf(sc, a3, bb.w);
        if (RELU) {
            o0 = fmaxf(o0, 0.f); o1 = fmaxf(o1, 0.f);
            o2 = fmaxf(o2, 0.f); o3 = fmaxf(o3, 0.f);
        }
        if constexpr (OUT_BF16) {
            uint2 o;
            o.x = f2bf(o0) | (f2bf(o1) << 16);
            o.y = f2bf(o2) | (f2bf(o3) << 16);
            ((uint2*)outv)[(size_t)d * 32 + h] = o;
        } else {
            ((float4*)outv)[(size_t)d * 32 + h] = make_float4(o0, o1, o2, o3);
        }
    }
}

// ---------------------------------------------------------------------------
// 6) logits = x_emb @ Wl + bl; log_softmax over 40 cols.
// ---------------------------------------------------------------------------
__global__ __launch_bounds__(256) void logits_lsm_k(const float* __restrict__ xe,
                                                    const float* __restrict__ Wl,
                                                    const float* __restrict__ bl,
                                                    float* __restrict__ out, int M) {
    __shared__ float sW[128 * 40];
    __shared__ float sX[32][132];
    __shared__ float sB[40];
    const int tid = threadIdx.x;
    const int row0 = blockIdx.x * 32;

    for (int i = tid; i < (128 * 40) / 4; i += 256)
        ((float4*)sW)[i] = ((const float4*)Wl)[i];
    if (tid < 40) sB[tid] = bl[tid];
    for (int i = tid; i < 32 * 32; i += 256) {
        int r = i >> 5, cq = i & 31;
        float4 v = make_float4(0.f, 0.f, 0.f, 0.f);
        if (row0 + r < M) v = *(const float4*)&xe[(size_t)(row0 + r) * 128 + cq * 4];
        *(float4*)&sX[r][cq * 4] = v;
    }
    __syncthreads();

    const int g = tid >> 3;  // local row 0..31
    const int l = tid & 7;   // lane-in-row
    const int row = row0 + g;
    float acc[5] = {0.f, 0.f, 0.f, 0.f, 0.f};
    for (int k = 0; k < 128; ++k) {
        float xv = sX[g][k];
        const float* w = &sW[k * 40 + l * 5];
#pragma unroll
        for (int j = 0; j < 5; ++j) acc[j] = fmaf(xv, w[j], acc[j]);
    }
#pragma unroll
    for (int j = 0; j < 5; ++j) acc[j] += sB[l * 5 + j];

    float m = acc[0];
#pragma unroll
    for (int j = 1; j < 5; ++j) m = fmaxf(m, acc[j]);
#pragma unroll
    for (int off = 1; off < 8; off <<= 1) m = fmaxf(m, __shfl_xor(m, off));
    float s = 0.f;
#pragma unroll
    for (int j = 0; j < 5; ++j) s += expf(acc[j] - m);
#pragma unroll
    for (int off = 1; off < 8; off <<= 1) s += __shfl_xor(s, off);
    float lse = m + logf(s);
    if (row < M) {
#pragma unroll
        for (int j = 0; j < 5; ++j) out[(size_t)row * 40 + l * 5 + j] = acc[j] - lse;
    }
}

// ---------------------------------------------------------------------------
// launch
// ---------------------------------------------------------------------------
extern "C" void kernel_launch(void* const* d_in, const int* in_sizes, int n_in,
                              void* d_out, int out_size, void* d_ws, size_t ws_size,
                              hipStream_t stream) {
    const float* x  = (const float*)d_in[0];
    const int*   ei = (const int*)d_in[1];
    const float* W1 = (const float*)d_in[2];
    const float* b1 = (const float*)d_in[3];
    const float* W2 = (const float*)d_in[4];
    const float* b2 = (const float*)d_in[5];
    const float* Wl = (const float*)d_in[6];
    const float* bl = (const float*)d_in[7];

    const int N = in_sizes[0] / FDIM;   // 50000
    const int E = in_sizes[1] / 2;      // 600000
    const int* src = ei;
    const int* dst = ei + E;

    float* out_lsm = (float*)d_out;                    // [N,40]
    float* x_emb   = (float*)d_out + (size_t)N * ODIM; // [N,128]

    // workspace layout
    char* w = (char*)d_ws;
    int* count  = (int*)w;              // N
    int* rowptr = count + N;            // N+1
    int* cursor = rowptr + N + 1;       // N
    int* csr    = cursor + N;           // E
    float* dinv = (float*)(csr + E);    // N
    int* blockSums = (int*)(dinv + N);  // 64
    unsigned short* Wt1 = (unsigned short*)(blockSums + 64);  // 16384 bf16
    unsigned short* Wt2 = Wt1 + 128 * 128;                    // 16384 bf16
    size_t small_bytes = (size_t)4 * ((size_t)N + (N + 1) + N + E + N + 64) + 2 * 128 * 128 * 2;
    size_t off = (small_bytes + 255) & ~(size_t)255;
    unsigned* bufA = (unsigned*)(w + off);       // N*64 uints (g, bf16x2)
    unsigned* bufB = bufA + (size_t)N * 64;      // N*64 uints (h, bf16x2)

    const int nchunk = (N + 1023) / 1024;        // 49 for N=50000 (<=64 required)

    hipMemsetAsync(count, 0, (size_t)N * sizeof(int), stream);
    count_edges_k<<<(E + 255) / 256, 256, 0, stream>>>(dst, count, E);
    block_sum_k<<<nchunk, 256, 0, stream>>>(count, blockSums, dinv, N);
    scan_sums_k<<<1, 64, 0, stream>>>(blockSums, nchunk, rowptr, N);
    scan_chunk_k<<<nchunk, 256, 0, stream>>>(count, blockSums, rowptr, cursor, N);
    fill_csr_k<<<(E + 255) / 256, 256, 0, stream>>>(src, dst, cursor, csr, E);
    convert_wt2_k<<<128, 256, 0, stream>>>(W1, W2, Wt1, Wt2);

    int gblocks = (N + 63) / 64;
    int ablocks = (N + 1) / 2;
    // layer 1
    mfma_gemm_k<float><<<gblocks, 256, 0, stream>>>(x, Wt1, dinv, (unsigned short*)bufA, N);
    aggregate2_k<true, true><<<ablocks, 64, 0, stream>>>(
        (const uint2*)bufA, dinv, rowptr, csr, b1, bufB, N);
    // layer 2
    mfma_gemm_k<unsigned short><<<gblocks, 256, 0, stream>>>(
        (const unsigned short*)bufB, Wt2, dinv, (unsigned short*)bufA, N);
    aggregate2_k<false, false><<<ablocks, 64, 0, stream>>>(
        (const uint2*)bufA, dinv, rowptr, csr, b2, x_emb, N);
    // head
    logits_lsm_k<<<(N + 31) / 32, 256, 0, stream>>>(x_emb, Wl, bl, out_lsm, N);
}